// Round 6
// baseline (129.297 us; speedup 1.0000x reference)
//
#include <hip/hip_runtime.h>
#include <hip/hip_cooperative_groups.h>
#include <math.h>

namespace cg = cooperative_groups;

#define NB 8
#define ND 64
#define NS 512

typedef __attribute__((ext_vector_type(8))) short bf16x8;
typedef __attribute__((ext_vector_type(4))) float f32x4;
typedef __attribute__((ext_vector_type(4))) unsigned short us4;
typedef __attribute__((ext_vector_type(8))) unsigned short us8;

__device__ __forceinline__ unsigned short f2bf(float f) {
    unsigned int u = __float_as_uint(f);
    unsigned int r = (u + 0x7FFFu + ((u >> 16) & 1u)) >> 16;   // RNE
    return (unsigned short)r;
}

// One cooperative kernel, 256 blocks x 256 threads (1 block/CU).
// Phase 1: a/b = x^T W via MFMA (LDS-transposed x,W tiles) -> a_bf,b_bf,na,nb;
//          plus x->x_bf conversion and rs rowsums (2 d-rows per block).
// Phase 2: per live 64x64 (i,w) tile: S = b·a^T (MFMA), wm = -sqrt(na+nb+2S)
//          masked -> bf16 swizzled LDS -> part = wm·x^T (MFMA), disjoint stores.
// Phase 3: out[b,d,i] = rs[b,d] + sum_{u >= i>>6} part[u][b][d][i].
__global__ __launch_bounds__(256) void k_all(const float* __restrict__ x,
                                             const float* __restrict__ W,
                                             unsigned short* __restrict__ a_bf,
                                             unsigned short* __restrict__ b_bf,
                                             float* __restrict__ na,
                                             float* __restrict__ nb,
                                             unsigned short* __restrict__ x_bf,
                                             float* __restrict__ rs,
                                             float* __restrict__ part,
                                             float* __restrict__ out) {
    __shared__ unsigned short xT[16 * 64];      // [j][d] bf16, XOR-swizzled 16B groups
    __shared__ unsigned short WT[128 * 64];     // [n][d] bf16, XOR-swizzled
    __shared__ float nsh[4][16];
    __shared__ unsigned short wm_lds[64 * 64];

    int bid  = blockIdx.x;
    int t    = threadIdx.x;
    int lane = t & 63, wv = t >> 6, c = lane & 15, g = lane >> 4;

    // ===================== PHASE 1 =====================
    {
        int b   = bid >> 5;
        int sub = bid & 31;
        int j0  = sub * 16;

        // x -> x_bf + rowsum (2 d-rows per block)
        if (t < 128) {
            int grp = t >> 6, l = t & 63;
            int d = 2 * sub + grp;
            const float4* xr4 = (const float4*)(x + ((size_t)(b * ND + d)) * NS);
            float4 v0 = xr4[2 * l];
            float4 v1 = xr4[2 * l + 1];
            float s = v0.x + v0.y + v0.z + v0.w + v1.x + v1.y + v1.z + v1.w;
#pragma unroll
            for (int m = 32; m >= 1; m >>= 1) s += __shfl_xor(s, m, 64);
            us8 h;
            h[0] = f2bf(v0.x); h[1] = f2bf(v0.y); h[2] = f2bf(v0.z); h[3] = f2bf(v0.w);
            h[4] = f2bf(v1.x); h[5] = f2bf(v1.y); h[6] = f2bf(v1.z); h[7] = f2bf(v1.w);
            *(us8*)(x_bf + ((size_t)(b * ND + d)) * NS + l * 8) = h;
            if (l == 0) rs[b * ND + d] = s;
        }

        // stage xT[16j][64d] (swizzled): thread = (j, dgrp, half), 4 d's each
        {
            int j = t & 15, dg = (t >> 4) & 7, half = t >> 7;
            us4 h;
#pragma unroll
            for (int dd = 0; dd < 4; ++dd)
                h[dd] = f2bf(x[((size_t)(b * ND) + dg * 8 + half * 4 + dd) * NS + j0 + j]);
            *(us4*)&xT[j * 64 + ((dg ^ (j & 7)) << 3) + half * 4] = h;
        }
        // stage WT[128n][64d] (swizzled): n<64 -> W_w^T, n>=64 -> W_h^T
        {
            int n = t & 127, half = t >> 7;
#pragma unroll
            for (int p = 0; p < 4; ++p) {
                int dg = half * 4 + p;
                us8 h;
#pragma unroll
                for (int dd = 0; dd < 8; ++dd)
                    h[dd] = f2bf(W[(size_t)(dg * 8 + dd) * ND + (n & 63) + ((n >> 6) * 4096)]);
                *(us8*)&WT[n * 64 + ((dg ^ (n & 7)) << 3)] = h;
            }
        }
        __syncthreads();

        // MFMA: C[j][n] = sum_d xT[j][d] * WT[n][d]; wave wv owns n in [32wv, 32wv+32)
        f32x4 acc[2] = {{0.f, 0.f, 0.f, 0.f}, {0.f, 0.f, 0.f, 0.f}};
#pragma unroll
        for (int ks = 0; ks < 2; ++ks) {
            bf16x8 P = *(bf16x8*)&xT[c * 64 + ((((ks << 2) | g) ^ (c & 7)) << 3)];
#pragma unroll
            for (int nt = 0; nt < 2; ++nt) {
                int rw = 32 * wv + 16 * nt + c;
                bf16x8 Q = *(bf16x8*)&WT[rw * 64 + ((((ks << 2) | g) ^ (rw & 7)) << 3)];
                acc[nt] = __builtin_amdgcn_mfma_f32_16x16x32_bf16(P, Q, acc[nt], 0, 0, 0);
            }
        }
        // norm partials (f32, pre-rounding): reduce over the 16 c-lanes
#pragma unroll
        for (int r = 0; r < 4; ++r) {
            float s = acc[0][r] * acc[0][r] + acc[1][r] * acc[1][r];
#pragma unroll
            for (int msk = 1; msk <= 8; msk <<= 1) s += __shfl_xor(s, msk, 64);
            if (c == 0) nsh[wv][4 * g + r] = s;
        }
        // bf16 stores of a (wv 0,1) / b (wv 2,3): row j = j0+4g+r, col kb+16nt+c
        {
            unsigned short* dst = (wv < 2) ? a_bf : b_bf;
            int kb = (wv & 1) * 32;
#pragma unroll
            for (int nt = 0; nt < 2; ++nt)
#pragma unroll
                for (int r = 0; r < 4; ++r)
                    dst[((size_t)b * NS + j0 + 4 * g + r) * ND + kb + 16 * nt + c] =
                        f2bf(acc[nt][r]);
        }
        __syncthreads();
        if (t < 32) {
            int jj = t & 15;
            if (t < 16) na[b * NS + j0 + jj] = nsh[0][jj] + nsh[1][jj];
            else        nb[b * NS + j0 + jj] = nsh[2][jj] + nsh[3][jj];
        }
    }

    __threadfence();
    cg::this_grid().sync();

    // ===================== PHASE 2 =====================
    for (int uu = bid; uu < 288; uu += 256) {
        __syncthreads();                       // protect wm_lds across iterations
        int b2 = uu & 7, v = uu >> 3;
        int u2 = 0;
        while ((u2 + 1) * (u2 + 2) / 2 <= v) ++u2;   // w-tile
        int ti = v - u2 * (u2 + 1) / 2;              // i-tile (ti <= u2)
        int i0 = ti * 64, w0 = u2 * 64;

        bf16x8 afrag[2], bfrag[4][2], xfrag[4][2];
        {
            const unsigned short* bb = b_bf + ((size_t)(b2 * NS + w0 + 16 * wv + c)) * ND + g * 8;
            afrag[0] = *(const bf16x8*)(bb);
            afrag[1] = *(const bf16x8*)(bb + 32);
        }
#pragma unroll
        for (int n = 0; n < 4; ++n) {
            const unsigned short* aa = a_bf + ((size_t)(b2 * NS + i0 + 16 * n + c)) * ND + g * 8;
            bfrag[n][0] = *(const bf16x8*)(aa);
            bfrag[n][1] = *(const bf16x8*)(aa + 32);
        }
#pragma unroll
        for (int nd = 0; nd < 4; ++nd) {
            const unsigned short* xx = x_bf + ((size_t)(b2 * ND + 16 * nd + c)) * NS + w0 + 8 * g;
            xfrag[nd][0] = *(const bf16x8*)(xx);
            xfrag[nd][1] = *(const bf16x8*)(xx + 32);
        }
        float nbv[4], nav[4];
#pragma unroll
        for (int r = 0; r < 4; ++r) nbv[r] = nb[b2 * NS + w0 + 16 * wv + 4 * g + r];
#pragma unroll
        for (int n = 0; n < 4; ++n) nav[n] = na[b2 * NS + i0 + 16 * n + c];

        int wbase = w0 + 16 * wv + 4 * g;
#pragma unroll
        for (int n = 0; n < 4; ++n) {
            f32x4 a1 = {0.f, 0.f, 0.f, 0.f};
            a1 = __builtin_amdgcn_mfma_f32_16x16x32_bf16(afrag[0], bfrag[n][0], a1, 0, 0, 0);
            a1 = __builtin_amdgcn_mfma_f32_16x16x32_bf16(afrag[1], bfrag[n][1], a1, 0, 0, 0);
            int i_loc  = 16 * n + c;
            int i_glob = i0 + i_loc;
            us4 pk;
#pragma unroll
            for (int r = 0; r < 4; ++r) {
                float s2  = nav[n] + nbv[r] + 2.f * a1[r];
                float val = (i_glob <= wbase + r) ? -sqrtf(fmaxf(s2, 0.f)) : 0.f;
                pk[r] = f2bf(val);
            }
            int wblk = 2 * wv + (g >> 1);
            int hidx = i_loc * 64 + ((wblk ^ (i_loc & 7)) << 3) + 4 * (g & 1);
            *(us4*)(&wm_lds[hidx]) = pk;
        }
        __syncthreads();

        bf16x8 a2[2];
        {
            int il = 16 * wv + c;
#pragma unroll
            for (int s = 0; s < 2; ++s)
                a2[s] = *(const bf16x8*)(&wm_lds[il * 64 + (((4 * s + g) ^ (il & 7)) << 3)]);
        }
#pragma unroll
        for (int nd = 0; nd < 4; ++nd) {
            f32x4 a3 = {0.f, 0.f, 0.f, 0.f};
            a3 = __builtin_amdgcn_mfma_f32_16x16x32_bf16(a2[0], xfrag[nd][0], a3, 0, 0, 0);
            a3 = __builtin_amdgcn_mfma_f32_16x16x32_bf16(a2[1], xfrag[nd][1], a3, 0, 0, 0);
            int d = 16 * nd + c;
            float* pp = part + (((size_t)u2 * NB + b2) * ND + d) * NS + i0 + 16 * wv + 4 * g;
            *(f32x4*)pp = a3;
        }
    }

    __threadfence();
    cg::this_grid().sync();

    // ===================== PHASE 3 =====================
#pragma unroll
    for (int e = 0; e < 2; ++e) {
        int unit = bid * 2 + e;               // 0..511 = (b,d)
        int b3 = unit >> 6, d = unit & 63;
        float r0 = rs[b3 * ND + d];
#pragma unroll
        for (int q = 0; q < 2; ++q) {
            int i  = t + q * 256;
            int it = i >> 6;
            float vsum = r0;
#pragma unroll
            for (int u3 = 0; u3 < 8; ++u3) {
                if (u3 >= it)
                    vsum += part[(((size_t)u3 * NB + b3) * ND + d) * NS + i];
            }
            out[((size_t)b3 * ND + d) * NS + i] = vsum;
        }
    }
}

extern "C" void kernel_launch(void* const* d_in, const int* in_sizes, int n_in,
                              void* d_out, int out_size, void* d_ws, size_t ws_size,
                              hipStream_t stream) {
    const float* x = (const float*)d_in[0];
    const float* W = (const float*)d_in[1];
    float* out = (float*)d_out;

    unsigned short* a_bf = (unsigned short*)d_ws;            // 512 KB
    unsigned short* b_bf = a_bf + (size_t)NB * NS * ND;      // 512 KB
    unsigned short* x_bf = b_bf + (size_t)NB * NS * ND;      // 512 KB
    float* na_p = (float*)(x_bf + (size_t)NB * NS * ND);     // 16 KB
    float* nb_p = na_p + NB * NS;                            // 16 KB
    float* rs_p = nb_p + NB * NS;                            // 2 KB
    float* part = rs_p + NB * ND;                            // 8 MB

    void* args[] = {(void*)&x, (void*)&W, (void*)&a_bf, (void*)&b_bf,
                    (void*)&na_p, (void*)&nb_p, (void*)&x_bf, (void*)&rs_p,
                    (void*)&part, (void*)&out};
    hipLaunchCooperativeKernel((const void*)k_all, dim3(256), dim3(256), args, 0, stream);
}

// Round 7
// 34.561 us; speedup vs baseline: 3.7412x; 3.7412x over previous
//
#include <hip/hip_runtime.h>
#include <math.h>

#define NB 8
#define ND 64
#define NS 512

typedef __attribute__((ext_vector_type(8))) short bf16x8;
typedef __attribute__((ext_vector_type(4))) float f32x4;
typedef __attribute__((ext_vector_type(4))) unsigned short us4;
typedef __attribute__((ext_vector_type(8))) unsigned short us8;

__device__ __forceinline__ unsigned short f2bf(float f) {
    unsigned int u = __float_as_uint(f);
    unsigned int r = (u + 0x7FFFu + ((u >> 16) & 1u)) >> 16;   // RNE
    return (unsigned short)r;
}

#define MFMA __builtin_amdgcn_mfma_f32_16x16x32_bf16

// One plain kernel, 64 blocks x 256 threads. Block (b, ti) owns out[b,:,64ti..64ti+63].
// Everything computed in-block: W^T staged once; per w-tile u>=ti the x tile is staged
// in both orientations, b-rows (and a-rows on the diagonal tile) computed via MFMA,
// then S=b·a^T -> wm=-sqrt(na+nb+2S) masked -> c-partials accumulated in registers.
__global__ __launch_bounds__(256) void k_fused(const float* __restrict__ x,
                                               const float* __restrict__ W,
                                               float* __restrict__ out) {
    __shared__ unsigned short WT[128 * 64];   // [n][d] swizzled; n<64: W_w col, n>=64: W_h col
    __shared__ unsigned short xdw[64 * 64];   // [d][w_loc] swizzled (per tile)
    __shared__ unsigned short xwd[64 * 64];   // [w_loc][d] swizzled (per tile)
    __shared__ unsigned short alds[64 * 64];  // [j_loc][k] swizzled (diagonal tile only)
    __shared__ unsigned short blds[64 * 64];  // [w_loc][k] swizzled (per tile)
    __shared__ unsigned short wm[64 * 64];    // [i_loc][w_loc] swizzled (per tile)
    __shared__ float na_lds[64], nb_lds[64], rs_lds[64];

    int bid = blockIdx.x;
    int b = bid >> 3, ti = bid & 7;
    int i0 = ti * 64;
    int t = threadIdx.x;
    int lane = t & 63, wv = t >> 6, c = lane & 15, g = lane >> 4;
    int c7 = c & 7;

    // ---- stage W^T (bf16, swizzled) ----
    {
        int n = t & 127, half = t >> 7;
#pragma unroll
        for (int p = 0; p < 4; ++p) {
            int dg = half * 4 + p;
            us8 h;
#pragma unroll
            for (int dd = 0; dd < 8; ++dd)
                h[dd] = f2bf(W[(size_t)(dg * 8 + dd) * ND + (n & 63) + ((n >> 6) * 4096)]);
            *(us8*)&WT[n * 64 + ((dg ^ (n & 7)) << 3)] = h;
        }
    }
    // ---- rowsum rs[d] = sum_w x[b][d][w] ----
    {
        int d = t >> 2, wq = t & 3;
        const float* xr = x + ((size_t)(b * ND) + d) * NS;
        float s = 0.f;
#pragma unroll
        for (int q = 0; q < 32; ++q) {
            float4 v = *(const float4*)(xr + 4 * wq + 16 * q);
            s += v.x + v.y + v.z + v.w;
        }
        s += __shfl_xor(s, 1, 64);
        s += __shfl_xor(s, 2, 64);
        if (wq == 0) rs_lds[d] = s;
    }

    f32x4 accc[4] = {{0.f,0.f,0.f,0.f},{0.f,0.f,0.f,0.f},{0.f,0.f,0.f,0.f},{0.f,0.f,0.f,0.f}};

    for (int u = ti; u < 8; ++u) {
        int w0 = u * 64;
        __syncthreads();   // prev-iter readers of xdw/xwd/wm done (1st iter: WT/rs staged)

        // ---- stage xdw[d][w_loc] (coalesced f32x4) ----
#pragma unroll
        for (int q = 0; q < 2; ++q) {
            int e = t + 256 * q;           // 0..511
            int d = e >> 3, wc = e & 7;
            const float4* p = (const float4*)(x + ((size_t)(b * ND) + d) * NS + w0 + 8 * wc);
            float4 v0 = p[0], v1 = p[1];
            us8 h;
            h[0] = f2bf(v0.x); h[1] = f2bf(v0.y); h[2] = f2bf(v0.z); h[3] = f2bf(v0.w);
            h[4] = f2bf(v1.x); h[5] = f2bf(v1.y); h[6] = f2bf(v1.z); h[7] = f2bf(v1.w);
            *(us8*)&xdw[d * 64 + ((wc ^ (d & 7)) << 3)] = h;
        }
        // ---- build xwd[w_loc][d] directly from global (row-reads are coalesced) ----
        {
            int wl = t & 63, w2 = t >> 6;
#pragma unroll
            for (int j = 0; j < 2; ++j) {
                us8 h;
#pragma unroll
                for (int e = 0; e < 8; ++e) {
                    int d = 16 * w2 + 8 * j + e;
                    h[e] = f2bf(x[((size_t)(b * ND) + d) * NS + w0 + wl]);
                }
                *(us8*)&xwd[wl * 64 + (((2 * w2 + j) ^ (wl & 7)) << 3)] = h;
            }
        }
        __syncthreads();

        // ---- a-GEMM (diagonal tile only): a[j][k] = sum_d x[d][i0+j] W_w[d][k] ----
        if (u == ti) {
            f32x4 acc[4] = {{0.f,0.f,0.f,0.f},{0.f,0.f,0.f,0.f},{0.f,0.f,0.f,0.f},{0.f,0.f,0.f,0.f}};
#pragma unroll
            for (int s2 = 0; s2 < 2; ++s2) {
                bf16x8 P = *(const bf16x8*)&xwd[(16 * wv + c) * 64 + (((4 * s2 + g) ^ c7) << 3)];
#pragma unroll
                for (int qb = 0; qb < 4; ++qb) {
                    bf16x8 Q = *(const bf16x8*)&WT[(16 * qb + c) * 64 + (((4 * s2 + g) ^ c7) << 3)];
                    acc[qb] = MFMA(P, Q, acc[qb], 0, 0, 0);
                }
            }
#pragma unroll
            for (int r = 0; r < 4; ++r) {
                float sq = acc[0][r] * acc[0][r] + acc[1][r] * acc[1][r]
                         + acc[2][r] * acc[2][r] + acc[3][r] * acc[3][r];
                sq += __shfl_xor(sq, 1, 64); sq += __shfl_xor(sq, 2, 64);
                sq += __shfl_xor(sq, 4, 64); sq += __shfl_xor(sq, 8, 64);
                if (c == 0) na_lds[16 * wv + 4 * g + r] = sq;
            }
#pragma unroll
            for (int qb = 0; qb < 4; ++qb)
#pragma unroll
                for (int r = 0; r < 4; ++r) {
                    int row = 16 * wv + 4 * g + r, k = 16 * qb + c;
                    alds[row * 64 + (((k >> 3) ^ (row & 7)) << 3) + (k & 7)] = f2bf(acc[qb][r]);
                }
        }
        // ---- b-GEMM (every tile): b[w][k] = sum_d x[d][w0+w] W_h[d][k] ----
        {
            f32x4 acc[4] = {{0.f,0.f,0.f,0.f},{0.f,0.f,0.f,0.f},{0.f,0.f,0.f,0.f},{0.f,0.f,0.f,0.f}};
#pragma unroll
            for (int s2 = 0; s2 < 2; ++s2) {
                bf16x8 P = *(const bf16x8*)&xwd[(16 * wv + c) * 64 + (((4 * s2 + g) ^ c7) << 3)];
#pragma unroll
                for (int qb = 0; qb < 4; ++qb) {
                    bf16x8 Q = *(const bf16x8*)&WT[(64 + 16 * qb + c) * 64 + (((4 * s2 + g) ^ c7) << 3)];
                    acc[qb] = MFMA(P, Q, acc[qb], 0, 0, 0);
                }
            }
#pragma unroll
            for (int r = 0; r < 4; ++r) {
                float sq = acc[0][r] * acc[0][r] + acc[1][r] * acc[1][r]
                         + acc[2][r] * acc[2][r] + acc[3][r] * acc[3][r];
                sq += __shfl_xor(sq, 1, 64); sq += __shfl_xor(sq, 2, 64);
                sq += __shfl_xor(sq, 4, 64); sq += __shfl_xor(sq, 8, 64);
                if (c == 0) nb_lds[16 * wv + 4 * g + r] = sq;
            }
#pragma unroll
            for (int qb = 0; qb < 4; ++qb)
#pragma unroll
                for (int r = 0; r < 4; ++r) {
                    int row = 16 * wv + 4 * g + r, k = 16 * qb + c;
                    blds[row * 64 + (((k >> 3) ^ (row & 7)) << 3) + (k & 7)] = f2bf(acc[qb][r]);
                }
        }
        __syncthreads();

        // ---- GEMM1: S[w][i] = b[w,:]·a[i,:]; wm = masked -sqrt(na+nb+2S) ----
        {
            int wrow = 16 * wv + c;
            bf16x8 P0 = *(const bf16x8*)&blds[wrow * 64 + ((g ^ c7) << 3)];
            bf16x8 P1 = *(const bf16x8*)&blds[wrow * 64 + (((4 + g) ^ c7) << 3)];
            float nbv[4];
#pragma unroll
            for (int r = 0; r < 4; ++r) nbv[r] = nb_lds[16 * wv + 4 * g + r];
            int wbase = w0 + 16 * wv + 4 * g;
#pragma unroll
            for (int n = 0; n < 4; ++n) {
                int arow = 16 * n + c;
                f32x4 a1 = {0.f, 0.f, 0.f, 0.f};
                bf16x8 Q0 = *(const bf16x8*)&alds[arow * 64 + ((g ^ c7) << 3)];
                bf16x8 Q1 = *(const bf16x8*)&alds[arow * 64 + (((4 + g) ^ c7) << 3)];
                a1 = MFMA(P0, Q0, a1, 0, 0, 0);
                a1 = MFMA(P1, Q1, a1, 0, 0, 0);
                float navv = na_lds[arow];
                int i_glob = i0 + arow;
                us4 pk;
#pragma unroll
                for (int r = 0; r < 4; ++r) {
                    float s2v = navv + nbv[r] + 2.f * a1[r];
                    float val = (i_glob <= wbase + r) ? -sqrtf(fmaxf(s2v, 0.f)) : 0.f;
                    pk[r] = f2bf(val);
                }
                int wblk = 2 * wv + (g >> 1);
                *(us4*)&wm[arow * 64 + ((wblk ^ (arow & 7)) << 3) + 4 * (g & 1)] = pk;
            }
        }
        __syncthreads();

        // ---- GEMM2: accc[i][d] += wm[i,:]·x[d,:] over this tile's w ----
        {
            int il = 16 * wv + c;
            bf16x8 a20 = *(const bf16x8*)&wm[il * 64 + ((g ^ c7) << 3)];
            bf16x8 a21 = *(const bf16x8*)&wm[il * 64 + (((4 + g) ^ c7) << 3)];
#pragma unroll
            for (int nd = 0; nd < 4; ++nd) {
                int d = 16 * nd + c;
                bf16x8 q0 = *(const bf16x8*)&xdw[d * 64 + ((g ^ c7) << 3)];
                bf16x8 q1 = *(const bf16x8*)&xdw[d * 64 + (((4 + g) ^ c7) << 3)];
                accc[nd] = MFMA(a20, q0, accc[nd], 0, 0, 0);
                accc[nd] = MFMA(a21, q1, accc[nd], 0, 0, 0);
            }
        }
    }

    // ---- epilogue: out[b][d][i0+16wv+4g+r] = rs[d] + accc ----
#pragma unroll
    for (int nd = 0; nd < 4; ++nd) {
        int d = 16 * nd + c;
        float rsv = rs_lds[d];
        f32x4 o = accc[nd];
        o[0] += rsv; o[1] += rsv; o[2] += rsv; o[3] += rsv;
        *(f32x4*)(out + ((size_t)(b * ND) + d) * NS + i0 + 16 * wv + 4 * g) = o;
    }
}

extern "C" void kernel_launch(void* const* d_in, const int* in_sizes, int n_in,
                              void* d_out, int out_size, void* d_ws, size_t ws_size,
                              hipStream_t stream) {
    const float* x = (const float*)d_in[0];
    const float* W = (const float*)d_in[1];
    float* out = (float*)d_out;
    k_fused<<<dim3(NB * 8), dim3(256), 0, stream>>>(x, W, out);
}

// Round 8
// 28.795 us; speedup vs baseline: 4.4902x; 1.2002x over previous
//
#include <hip/hip_runtime.h>
#include <math.h>

#define NB 8
#define ND 64
#define NS 512

typedef __attribute__((ext_vector_type(8))) short bf16x8;
typedef __attribute__((ext_vector_type(4))) float f32x4;
typedef __attribute__((ext_vector_type(4))) unsigned short us4;
typedef __attribute__((ext_vector_type(8))) unsigned short us8;

__device__ __forceinline__ unsigned short f2bf(float f) {
    unsigned int u = __float_as_uint(f);
    unsigned int r = (u + 0x7FFFu + ((u >> 16) & 1u)) >> 16;   // RNE
    return (unsigned short)r;
}

#define MFMA __builtin_amdgcn_mfma_f32_16x16x32_bf16

// 64 blocks x 1024 threads. Block (b, ti) owns out[b,:,64ti..64ti+63].
// Wave-pair p handles w-tile u=p (active iff p>=ti) CONCURRENTLY:
//   stage xwd_p -> b-GEMM (pair0 also a-GEMM) -> blds_p -> GEMM1 -> wm_p
//   -> GEMM2 (x from global) -> f32 partial -> cross-pair LDS reduction.
__global__ __launch_bounds__(1024, 4) void k_one(const float* __restrict__ x,
                                                 const float* __restrict__ W,
                                                 float* __restrict__ out) {
    __shared__ __align__(16) unsigned short WT[128 * 64];        // 16 KB [n][d] swz
    __shared__ __align__(16) unsigned short pairbuf[8][64 * 64]; // 64 KB, multi-use
    __shared__ __align__(16) unsigned short alds[64 * 64];       // 8 KB  [i][k] swz
    __shared__ float na_lds[64];
    __shared__ float nb_lds[8][64];
    __shared__ float rs_lds[64];

    int bid = blockIdx.x;
    int b = bid >> 3, ti = bid & 7;
    int i0 = ti * 64;
    int t = threadIdx.x;
    int wave = t >> 6;            // 0..15
    int p = wave >> 1;            // pair = u-tile 0..7
    int wl = wave & 1;            // wave within pair
    int lane = t & 63, c = lane & 15, g = lane >> 4, c7 = c & 7;
    bool act = (p >= ti);
    int w0 = p * 64;

    // ---------------- prologue ----------------
    // WT[n][d] (n<64: W_w col n; n>=64: W_h col n), swizzled us8 writes
    {
        int n = t & 127, dg = t >> 7;             // dg 0..7
        us8 h;
#pragma unroll
        for (int dd = 0; dd < 8; ++dd)
            h[dd] = f2bf(W[(size_t)(dg * 8 + dd) * ND + (n & 63) + ((n >> 6) * (ND * ND))]);
        *(us8*)&WT[n * 64 + ((dg ^ (n & 7)) << 3)] = h;
    }
    // rowsum rs[d]
    {
        int d = t >> 4, q = t & 15;
        const float* xr = x + ((size_t)(b * ND) + d) * NS + q * 32;
        float s = 0.f;
#pragma unroll
        for (int e = 0; e < 8; ++e) {
            float4 v = *(const float4*)(xr + 4 * e);
            s += v.x + v.y + v.z + v.w;
        }
        s += __shfl_xor(s, 1, 64); s += __shfl_xor(s, 2, 64);
        s += __shfl_xor(s, 4, 64); s += __shfl_xor(s, 8, 64);
        if (q == 0) rs_lds[d] = s;
    }
    // xwd_p[w_loc][d] (active pairs), coalesced row reads
    if (act) {
        int tt = t & 127;
        int wlc = tt & 63, half = tt >> 6;
#pragma unroll
        for (int j = 0; j < 4; ++j) {
            int dblk = 4 * half + j;
            us8 h;
#pragma unroll
            for (int e = 0; e < 8; ++e)
                h[e] = f2bf(x[((size_t)(b * ND) + dblk * 8 + e) * NS + w0 + wlc]);
            *(us8*)&pairbuf[p][wlc * 64 + ((dblk ^ (wlc & 7)) << 3)] = h;
        }
    }
    __syncthreads();   // S1

    // ---------------- phase A: b-GEMM (+ a-GEMM on pair 0) ----------------
    f32x4 bacc[2][4];
    if (act) {
#pragma unroll
        for (int pg2 = 0; pg2 < 2; ++pg2)
#pragma unroll
            for (int qg = 0; qg < 4; ++qg) bacc[pg2][qg] = f32x4{0.f, 0.f, 0.f, 0.f};
#pragma unroll
        for (int ks = 0; ks < 2; ++ks)
#pragma unroll
            for (int pg2 = 0; pg2 < 2; ++pg2) {
                int wrow = 16 * (2 * wl + pg2) + c;
                bf16x8 P = *(const bf16x8*)&pairbuf[p][wrow * 64 + (((4 * ks + g) ^ c7) << 3)];
#pragma unroll
                for (int qg = 0; qg < 4; ++qg) {
                    bf16x8 Q = *(const bf16x8*)&WT[(64 + 16 * qg + c) * 64 + (((4 * ks + g) ^ c7) << 3)];
                    bacc[pg2][qg] = MFMA(P, Q, bacc[pg2][qg], 0, 0, 0);
                }
            }
#pragma unroll
        for (int pg2 = 0; pg2 < 2; ++pg2)
#pragma unroll
            for (int r = 0; r < 4; ++r) {
                float sq = bacc[pg2][0][r] * bacc[pg2][0][r] + bacc[pg2][1][r] * bacc[pg2][1][r]
                         + bacc[pg2][2][r] * bacc[pg2][2][r] + bacc[pg2][3][r] * bacc[pg2][3][r];
                sq += __shfl_xor(sq, 1, 64); sq += __shfl_xor(sq, 2, 64);
                sq += __shfl_xor(sq, 4, 64); sq += __shfl_xor(sq, 8, 64);
                if (c == 0) nb_lds[p][16 * (2 * wl + pg2) + 4 * g + r] = sq;
            }
    }
    if (p == 0) {      // a-GEMM over diagonal x-tile (pairbuf[ti])
        f32x4 aacc[2][4];
#pragma unroll
        for (int pg2 = 0; pg2 < 2; ++pg2)
#pragma unroll
            for (int qg = 0; qg < 4; ++qg) aacc[pg2][qg] = f32x4{0.f, 0.f, 0.f, 0.f};
#pragma unroll
        for (int ks = 0; ks < 2; ++ks)
#pragma unroll
            for (int pg2 = 0; pg2 < 2; ++pg2) {
                int irow = 16 * (2 * wl + pg2) + c;
                bf16x8 P = *(const bf16x8*)&pairbuf[ti][irow * 64 + (((4 * ks + g) ^ c7) << 3)];
#pragma unroll
                for (int qg = 0; qg < 4; ++qg) {
                    bf16x8 Q = *(const bf16x8*)&WT[(16 * qg + c) * 64 + (((4 * ks + g) ^ c7) << 3)];
                    aacc[pg2][qg] = MFMA(P, Q, aacc[pg2][qg], 0, 0, 0);
                }
            }
#pragma unroll
        for (int pg2 = 0; pg2 < 2; ++pg2)
#pragma unroll
            for (int r = 0; r < 4; ++r) {
                float sq = aacc[pg2][0][r] * aacc[pg2][0][r] + aacc[pg2][1][r] * aacc[pg2][1][r]
                         + aacc[pg2][2][r] * aacc[pg2][2][r] + aacc[pg2][3][r] * aacc[pg2][3][r];
                sq += __shfl_xor(sq, 1, 64); sq += __shfl_xor(sq, 2, 64);
                sq += __shfl_xor(sq, 4, 64); sq += __shfl_xor(sq, 8, 64);
                if (c == 0) na_lds[16 * (2 * wl + pg2) + 4 * g + r] = sq;
            }
#pragma unroll
        for (int pg2 = 0; pg2 < 2; ++pg2)
#pragma unroll
            for (int qg = 0; qg < 4; ++qg)
#pragma unroll
                for (int r = 0; r < 4; ++r) {
                    int row = 16 * (2 * wl + pg2) + 4 * g + r, k = 16 * qg + c;
                    alds[row * 64 + (((k >> 3) ^ (row & 7)) << 3) + (k & 7)] = f2bf(aacc[pg2][qg][r]);
                }
    }
    __syncthreads();   // S2: all xwd reads done

    // ---------------- phase B: write blds_p over xwd_p ----------------
    if (act) {
#pragma unroll
        for (int pg2 = 0; pg2 < 2; ++pg2)
#pragma unroll
            for (int qg = 0; qg < 4; ++qg)
#pragma unroll
                for (int r = 0; r < 4; ++r) {
                    int row = 16 * (2 * wl + pg2) + 4 * g + r, k = 16 * qg + c;
                    pairbuf[p][row * 64 + (((k >> 3) ^ (row & 7)) << 3) + (k & 7)] = f2bf(bacc[pg2][qg][r]);
                }
    }
    __syncthreads();   // S3

    // ---------------- phase C: GEMM1 -> wm_p ----------------
    f32x4 sacc[2][4];
    if (act) {
#pragma unroll
        for (int pg2 = 0; pg2 < 2; ++pg2)
#pragma unroll
            for (int qi = 0; qi < 4; ++qi) sacc[pg2][qi] = f32x4{0.f, 0.f, 0.f, 0.f};
#pragma unroll
        for (int ks = 0; ks < 2; ++ks)
#pragma unroll
            for (int pg2 = 0; pg2 < 2; ++pg2) {
                int wrow = 16 * (2 * wl + pg2) + c;
                bf16x8 P = *(const bf16x8*)&pairbuf[p][wrow * 64 + (((4 * ks + g) ^ c7) << 3)];
#pragma unroll
                for (int qi = 0; qi < 4; ++qi) {
                    int irow = 16 * qi + c;
                    bf16x8 Q = *(const bf16x8*)&alds[irow * 64 + (((4 * ks + g) ^ c7) << 3)];
                    sacc[pg2][qi] = MFMA(P, Q, sacc[pg2][qi], 0, 0, 0);
                }
            }
    }
    __syncthreads();   // S4: all blds reads done
    if (act) {
#pragma unroll
        for (int pg2 = 0; pg2 < 2; ++pg2) {
            int wgrp = 2 * wl + pg2;
            float nbv[4];
#pragma unroll
            for (int r = 0; r < 4; ++r) nbv[r] = nb_lds[p][16 * wgrp + 4 * g + r];
            int wbase = w0 + 16 * wgrp + 4 * g;
#pragma unroll
            for (int qi = 0; qi < 4; ++qi) {
                int i_loc = 16 * qi + c;
                int i_glob = i0 + i_loc;
                float navv = na_lds[i_loc];
                us4 pk;
#pragma unroll
                for (int r = 0; r < 4; ++r) {
                    float s2v = navv + nbv[r] + 2.f * sacc[pg2][qi][r];
                    float val = (i_glob <= wbase + r) ? -sqrtf(fmaxf(s2v, 0.f)) : 0.f;
                    pk[r] = f2bf(val);
                }
                int wblk = 2 * wgrp + (g >> 1);
                *(us4*)&pairbuf[p][i_loc * 64 + ((wblk ^ (i_loc & 7)) << 3) + 4 * (g & 1)] = pk;
            }
        }
    }
    __syncthreads();   // S5

    // ---------------- phase D: GEMM2 -> c^T partial [d][i] ----------------
    f32x4 cacc[2][4];  // d = 16*(2wl+pdl)+4g+r, i = 16*qi+c
    if (act) {
#pragma unroll
        for (int pdl = 0; pdl < 2; ++pdl)
#pragma unroll
            for (int qi = 0; qi < 4; ++qi) cacc[pdl][qi] = f32x4{0.f, 0.f, 0.f, 0.f};
#pragma unroll
        for (int ks = 0; ks < 2; ++ks)
#pragma unroll
            for (int pdl = 0; pdl < 2; ++pdl) {
                int drow = 16 * (2 * wl + pdl) + c;
                const float* xp = x + ((size_t)(b * ND) + drow) * NS + w0 + 32 * ks + 8 * g;
                float4 v0 = *(const float4*)xp;
                float4 v1 = *(const float4*)(xp + 4);
                bf16x8 P;
                P[0] = (short)f2bf(v0.x); P[1] = (short)f2bf(v0.y);
                P[2] = (short)f2bf(v0.z); P[3] = (short)f2bf(v0.w);
                P[4] = (short)f2bf(v1.x); P[5] = (short)f2bf(v1.y);
                P[6] = (short)f2bf(v1.z); P[7] = (short)f2bf(v1.w);
#pragma unroll
                for (int qi = 0; qi < 4; ++qi) {
                    int irow = 16 * qi + c;
                    bf16x8 Q = *(const bf16x8*)&pairbuf[p][irow * 64 + (((4 * ks + g) ^ c7) << 3)];
                    cacc[pdl][qi] = MFMA(P, Q, cacc[pdl][qi], 0, 0, 0);
                }
            }
    }

    // ---------------- epilogue: 2-round cross-pair reduction ----------------
#pragma unroll
    for (int h = 0; h < 2; ++h) {
        __syncthreads();           // prior pairbuf readers done
        if (act && wl == h) {      // this wave holds d-half h
            float* pf = (float*)&pairbuf[p][0];
#pragma unroll
            for (int pdl = 0; pdl < 2; ++pdl)
#pragma unroll
                for (int qi = 0; qi < 4; ++qi)
#pragma unroll
                    for (int r = 0; r < 4; ++r) {
                        int dl = 16 * pdl + 4 * g + r;       // 0..31
                        int i  = 16 * qi + c;                // 0..63
                        int iq = i >> 2, il = i & 3;
                        pf[dl * 64 + ((iq ^ (dl & 15)) << 2) + il] = cacc[pdl][qi][r];
                    }
        }
        __syncthreads();
        if (t < 512) {
            int dl = t >> 4, iq = t & 15;
            f32x4 v = {0.f, 0.f, 0.f, 0.f};
#pragma unroll
            for (int pp = 0; pp < 8; ++pp) {
                if (pp >= ti) {
                    const float* pf = (const float*)&pairbuf[pp][0];
                    f32x4 rd = *(const f32x4*)&pf[dl * 64 + ((iq ^ (dl & 15)) << 2)];
                    v[0] += rd[0]; v[1] += rd[1]; v[2] += rd[2]; v[3] += rd[3];
                }
            }
            int d = 32 * h + dl;
            float rsv = rs_lds[d];
            v[0] += rsv; v[1] += rsv; v[2] += rsv; v[3] += rsv;
            *(f32x4*)&out[((size_t)(b * ND) + d) * NS + i0 + 4 * iq] = v;
        }
    }
}

extern "C" void kernel_launch(void* const* d_in, const int* in_sizes, int n_in,
                              void* d_out, int out_size, void* d_ws, size_t ws_size,
                              hipStream_t stream) {
    const float* x = (const float*)d_in[0];
    const float* W = (const float*)d_in[1];
    float* out = (float*)d_out;
    k_one<<<dim3(NB * 8), dim3(1024), 0, stream>>>(x, W, out);
}